// Round 6
// baseline (208.587 us; speedup 1.0000x reference)
//
#include <hip/hip_runtime.h>
#include <hip/hip_bf16.h>

#define IN_C 512
#define OUT_C 256
#define NN 8192
#define JSPL 8
#define JRANGE (NN / JSPL)       // 1024
#define NT (JRANGE / 32)         // 32 tiles of 32 k
#define L2E 1.44269504088896f

typedef __attribute__((ext_vector_type(8))) short s16x8;
typedef __attribute__((ext_vector_type(4))) float f32x4;

__device__ __forceinline__ ushort f2bf(float f) {
    unsigned u = __float_as_uint(f);
    unsigned r = (u + 0x7FFF + ((u >> 16) & 1)) >> 16;
    return (ushort)r;
}

// ---------------- Kernel A: h = x@W_fc + b_fc (fp32); store h bf16 in k-chunk-major
// tiles: hb[jt32][u][col] (uint4 = 8 bf16, k = jt32*32 + u*8 + e), u=0..3.
// Also s1 = h@Wa1+ba1, s2 = h@Wa2+ba2 ----------------
__global__ __launch_bounds__(256) void fc_kernel(
    const float* __restrict__ x, const float* __restrict__ Wfc,
    const float* __restrict__ bfc, const float* __restrict__ Wa1,
    const float* __restrict__ ba1, const float* __restrict__ Wa2,
    const float* __restrict__ ba2,
    uint4* __restrict__ hb,     // [NN/32][4][256] uint4
    float* __restrict__ s1, float* __restrict__ s2)
{
    __shared__ float xl[8 * IN_C];          // 16 KB
    __shared__ float red[2][8][4];
    const int t = threadIdx.x;
    const int r0 = blockIdx.x * 8;

    {
        const float4* src = (const float4*)(x + (size_t)r0 * IN_C);
        float4* dst = (float4*)xl;
        #pragma unroll
        for (int i = 0; i < 4; i++) dst[i * 256 + t] = src[i * 256 + t];
    }
    __syncthreads();

    float acc[8];
    #pragma unroll
    for (int r = 0; r < 8; r++) acc[r] = 0.f;

    for (int c4 = 0; c4 < IN_C / 4; c4++) {
        const float w0 = Wfc[(c4 * 4 + 0) * OUT_C + t];
        const float w1 = Wfc[(c4 * 4 + 1) * OUT_C + t];
        const float w2 = Wfc[(c4 * 4 + 2) * OUT_C + t];
        const float w3 = Wfc[(c4 * 4 + 3) * OUT_C + t];
        #pragma unroll
        for (int r = 0; r < 8; r++) {
            const float4 xv = *(const float4*)&xl[r * IN_C + c4 * 4];
            acc[r] = fmaf(xv.x, w0, acc[r]);
            acc[r] = fmaf(xv.y, w1, acc[r]);
            acc[r] = fmaf(xv.z, w2, acc[r]);
            acc[r] = fmaf(xv.w, w3, acc[r]);
        }
    }
    const float bb = bfc[t];
    #pragma unroll
    for (int r = 0; r < 8; r++) acc[r] += bb;

    // rows r0..r0+7 = k-chunk u=(r0>>3)&3 of 32-k tile jt32=r0>>5, col = t
    {
        union { ushort u[8]; uint4 v; } pk;
        #pragma unroll
        for (int r = 0; r < 8; r++) pk.u[r] = f2bf(acc[r]);
        const int jt = r0 >> 5, u = (r0 >> 3) & 3;
        hb[(size_t)jt * 1024 + u * 256 + t] = pk.v;
    }

    float p1[8], p2[8];
    const float wa1 = Wa1[t], wa2 = Wa2[t];
    #pragma unroll
    for (int r = 0; r < 8; r++) { p1[r] = acc[r] * wa1; p2[r] = acc[r] * wa2; }
    #pragma unroll
    for (int off = 32; off > 0; off >>= 1) {
        #pragma unroll
        for (int r = 0; r < 8; r++) {
            p1[r] += __shfl_down(p1[r], off);
            p2[r] += __shfl_down(p2[r], off);
        }
    }
    const int wv = t >> 6, ln = t & 63;
    if (ln == 0) {
        #pragma unroll
        for (int r = 0; r < 8; r++) { red[0][r][wv] = p1[r]; red[1][r][wv] = p2[r]; }
    }
    __syncthreads();
    if (t < 16) {
        const int s = t >> 3, r = t & 7;
        float v = red[s][r][0] + red[s][r][1] + red[s][r][2] + red[s][r][3];
        v += s ? ba2[0] : ba1[0];
        if (s) s2[r0 + r] = v; else s1[r0 + r] = v;
    }
}

// ---------------- Kernel A2: smax = max(s2) ----------------
__global__ __launch_bounds__(256) void smax_kernel(const float* __restrict__ s2,
                                                   float* __restrict__ smax)
{
    __shared__ float red[4];
    float m = -1e30f;
    for (int i = threadIdx.x; i < NN; i += 256) m = fmaxf(m, s2[i]);
    #pragma unroll
    for (int off = 32; off > 0; off >>= 1) m = fmaxf(m, __shfl_down(m, off));
    if ((threadIdx.x & 63) == 0) red[threadIdx.x >> 6] = m;
    __syncthreads();
    if (threadIdx.x == 0)
        smax[0] = fmaxf(fmaxf(red[0], red[1]), fmaxf(red[2], red[3]));
}

// ---------------- Kernel B: fused {adj ballot-pack} + {masked softmax-num @ h} ----------------
// grid (128, 8): 64 rows/block (4 waves x 16 rows), J-eighth per blockIdx.y.
// Phase 1: each wave streams contiguous 4-KB row bursts, __ballot -> 8 KB LDS bitmask.
// Phase 2: barrier-free MFMA loop; B-fragments read directly from L2-resident hb.
__global__ __launch_bounds__(256, 4) void attn_kernel(
    const int* __restrict__ adj, const uint4* __restrict__ hb,
    const float* __restrict__ s1, const float* __restrict__ s2,
    const float* __restrict__ smaxp, float* __restrict__ outp,
    float* __restrict__ pbase, float* __restrict__ rs)
{
    __shared__ float s2l[JRANGE];                     // 4 KB (pre-scaled by log2e)
    __shared__ unsigned long long mask_lds[64][16];   // 8 KB

    const int t = threadIdx.x;
    const int wave = t >> 6, lane = t & 63;
    const int g = lane >> 4, lr = lane & 15;
    const int jq = blockIdx.y;
    const int Jbase = jq * JRANGE;
    const int R0 = blockIdx.x * 64;
    const int row = R0 + wave * 16 + lr;

    // stage s2 slice, pre-scaled by log2(e)
    {
        const float4* src = (const float4*)(s2 + Jbase);
        float4* dst = (float4*)s2l;
        const float4 v = src[t];
        dst[t] = make_float4(v.x * L2E, v.y * L2E, v.z * L2E, v.w * L2E);
    }

    // ---- Phase 1: ballot-pack this block's adj slice (contiguous 4-KB bursts/row) ----
    {
        const int wrow0 = wave * 16;
        for (int r = 0; r < 16; ++r) {
            const int* arow = adj + (size_t)(R0 + wrow0 + r) * NN + Jbase + lane;
            int v[16];
            #pragma unroll
            for (int c = 0; c < 16; ++c)
                v[c] = __builtin_nontemporal_load(arow + c * 64);
            unsigned long long myw = 0;
            #pragma unroll
            for (int c = 0; c < 16; ++c) {
                const unsigned long long m = __ballot(v[c] > 0);
                if (lane == c) myw = m;
            }
            if (lane < 16) mask_lds[wrow0 + r][lane] = myw;
        }
    }

    const float my_s1 = s1[row] * L2E;
    const float z0 = my_s1 + smaxp[0] * L2E;
    const float m_i = fmaxf(z0, 0.01f * z0);   // scaled upper bound of masked row max

    f32x4 acc[16];
    #pragma unroll
    for (int n = 0; n < 16; n++) acc[n] = (f32x4)(0.f);
    float rsum = 0.f;

    const uint4* hb_base = hb + (size_t)(Jbase >> 5) * 1024;

    __syncthreads();   // mask + s2l ready (only barrier in the kernel)

    // ---- Phase 2: barrier-free MFMA tile loop, B-frags straight from L2 ----
    for (int tt = 0; tt < NT; ++tt) {
        const unsigned long long m64 = mask_lds[wave * 16 + lr][tt >> 1];
        const unsigned mb = (unsigned)(m64 >> ((tt & 1) * 32 + g * 8)) & 0xFFu;

        const int j0 = tt * 32 + g * 8;
        const float4 sva = *(const float4*)(s2l + j0);
        const float4 svb = *(const float4*)(s2l + j0 + 4);
        const float sv[8] = {sva.x, sva.y, sva.z, sva.w, svb.x, svb.y, svb.z, svb.w};
        union { ushort u[8]; s16x8 v; } pk;
        #pragma unroll
        for (int e = 0; e < 8; e++) {
            const float zz = my_s1 + sv[e];
            const float ee = fmaxf(zz, 0.01f * zz);   // leaky_relu (log2-scaled)
            float p = exp2f(ee - m_i);
            p = ((mb >> e) & 1u) ? p : 0.f;
            rsum += p;
            pk.u[e] = f2bf(p);
        }
        const s16x8 afrag = pk.v;

        const uint4* bsrc = hb_base + (size_t)tt * 1024 + g * 256 + lr;
        uint4 bf[8];
        #pragma unroll
        for (int n = 0; n < 8; n++) bf[n] = bsrc[n * 16];
        #pragma unroll
        for (int n = 0; n < 8; n++)
            acc[n] = __builtin_amdgcn_mfma_f32_16x16x32_bf16(afrag, *(const s16x8*)&bf[n], acc[n], 0, 0, 0);
        #pragma unroll
        for (int n = 0; n < 8; n++) bf[n] = bsrc[128 + n * 16];
        #pragma unroll
        for (int n = 0; n < 8; n++)
            acc[n + 8] = __builtin_amdgcn_mfma_f32_16x16x32_bf16(afrag, *(const s16x8*)&bf[n], acc[n + 8], 0, 0, 0);
    }

    // row-sum reduce across the 4 k-groups
    rsum += __shfl_xor(rsum, 16);
    rsum += __shfl_xor(rsum, 32);
    if (g == 0) rs[(size_t)jq * NN + row] = rsum;

    float* dst = (jq == 0) ? outp : (pbase + (size_t)(jq - 1) * ((size_t)NN * OUT_C));
    #pragma unroll
    for (int r = 0; r < 4; r++) {
        const int orow = R0 + wave * 16 + g * 4 + r;
        float* op = dst + (size_t)orow * OUT_C + lr;
        #pragma unroll
        for (int n = 0; n < 16; n++)
            __builtin_nontemporal_store(acc[n][r], op + n * 16);
    }
}

// ---------------- Kernel C: combine partials, normalize ----------------
__global__ __launch_bounds__(256) void combine_kernel(
    float* __restrict__ out, const float* __restrict__ pbase,
    const float* __restrict__ rs)
{
    const int row = blockIdx.x, t = threadIdx.x;
    float rsum = 0.f;
    #pragma unroll
    for (int q = 0; q < JSPL; q++) rsum += rs[(size_t)q * NN + row];
    const float inv = 1.f / rsum;
    const size_t idx = (size_t)row * OUT_C + t;
    const size_t stride = (size_t)NN * OUT_C;
    float v = out[idx];
    #pragma unroll
    for (int q = 0; q < JSPL - 1; q++)
        v += __builtin_nontemporal_load(&pbase[idx + (size_t)q * stride]);
    out[idx] = v * inv;
}

extern "C" void kernel_launch(void* const* d_in, const int* in_sizes, int n_in,
                              void* d_out, int out_size, void* d_ws, size_t ws_size,
                              hipStream_t stream) {
    const float* x   = (const float*)d_in[0];
    const int*   adj = (const int*)d_in[1];
    const float* Wfc = (const float*)d_in[2];
    const float* bfc = (const float*)d_in[3];
    const float* Wa1 = (const float*)d_in[4];
    const float* ba1 = (const float*)d_in[5];
    const float* Wa2 = (const float*)d_in[6];
    const float* ba2 = (const float*)d_in[7];
    float* out = (float*)d_out;

    char* ws = (char*)d_ws;
    uint4* hb   = (uint4*)ws;                        // 4 MiB   [256][4][256] uint4
    float* s1   = (float*)(ws + (4u << 20));         // 32 KiB
    float* s2   = s1 + NN;                           // 32 KiB
    float* rs   = s2 + NN;                           // 256 KiB [8][8192]
    float* smax = rs + JSPL * NN;                    // 4 B
    float* pbase = (float*)(ws + (5u << 20));        // 56 MiB  [7][8192][256] f32

    fc_kernel<<<dim3(NN / 8), 256, 0, stream>>>(x, Wfc, bfc, Wa1, ba1, Wa2, ba2, hb, s1, s2);
    smax_kernel<<<dim3(1), 256, 0, stream>>>(s2, smax);
    attn_kernel<<<dim3(NN / 64, JSPL), 256, 0, stream>>>(adj, hb, s1, s2, smax, out, pbase, rs);
    combine_kernel<<<dim3(NN), 256, 0, stream>>>(out, pbase, rs);
}

// Round 7
// 191.646 us; speedup vs baseline: 1.0884x; 1.0884x over previous
//
#include <hip/hip_runtime.h>
#include <hip/hip_bf16.h>

#define IN_C 512
#define OUT_C 256
#define NN 8192
#define JSPL 4
#define JRANGE (NN / JSPL)       // 2048
#define NT (JRANGE / 32)         // 64 tiles of 32 k
#define L2E 1.44269504088896f

typedef __attribute__((ext_vector_type(8))) short s16x8;
typedef __attribute__((ext_vector_type(4))) float f32x4;

__device__ __forceinline__ ushort f2bf(float f) {
    unsigned u = __float_as_uint(f);
    unsigned r = (u + 0x7FFF + ((u >> 16) & 1)) >> 16;
    return (ushort)r;
}

// ---------------- Kernel A: h = x@W_fc + b_fc (fp32); store h bf16 in k-chunk-major
// tiles: hb[jt32][u][col] (uint4 = 8 bf16, k = jt32*32 + u*8 + e), u=0..3.
// Also s1 = h@Wa1+ba1, s2 = h@Wa2+ba2 ----------------
__global__ __launch_bounds__(256) void fc_kernel(
    const float* __restrict__ x, const float* __restrict__ Wfc,
    const float* __restrict__ bfc, const float* __restrict__ Wa1,
    const float* __restrict__ ba1, const float* __restrict__ Wa2,
    const float* __restrict__ ba2,
    uint4* __restrict__ hb,     // [NN/32][4][256] uint4
    float* __restrict__ s1, float* __restrict__ s2)
{
    __shared__ float xl[8 * IN_C];          // 16 KB
    __shared__ float red[2][8][4];
    const int t = threadIdx.x;
    const int r0 = blockIdx.x * 8;

    {
        const float4* src = (const float4*)(x + (size_t)r0 * IN_C);
        float4* dst = (float4*)xl;
        #pragma unroll
        for (int i = 0; i < 4; i++) dst[i * 256 + t] = src[i * 256 + t];
    }
    __syncthreads();

    float acc[8];
    #pragma unroll
    for (int r = 0; r < 8; r++) acc[r] = 0.f;

    for (int c4 = 0; c4 < IN_C / 4; c4++) {
        const float w0 = Wfc[(c4 * 4 + 0) * OUT_C + t];
        const float w1 = Wfc[(c4 * 4 + 1) * OUT_C + t];
        const float w2 = Wfc[(c4 * 4 + 2) * OUT_C + t];
        const float w3 = Wfc[(c4 * 4 + 3) * OUT_C + t];
        #pragma unroll
        for (int r = 0; r < 8; r++) {
            const float4 xv = *(const float4*)&xl[r * IN_C + c4 * 4];
            acc[r] = fmaf(xv.x, w0, acc[r]);
            acc[r] = fmaf(xv.y, w1, acc[r]);
            acc[r] = fmaf(xv.z, w2, acc[r]);
            acc[r] = fmaf(xv.w, w3, acc[r]);
        }
    }
    const float bb = bfc[t];
    #pragma unroll
    for (int r = 0; r < 8; r++) acc[r] += bb;

    // rows r0..r0+7 = k-chunk u=(r0>>3)&3 of 32-k tile jt32=r0>>5, col = t
    {
        union { ushort u[8]; uint4 v; } pk;
        #pragma unroll
        for (int r = 0; r < 8; r++) pk.u[r] = f2bf(acc[r]);
        const int jt = r0 >> 5, u = (r0 >> 3) & 3;
        hb[(size_t)jt * 1024 + u * 256 + t] = pk.v;
    }

    float p1[8], p2[8];
    const float wa1 = Wa1[t], wa2 = Wa2[t];
    #pragma unroll
    for (int r = 0; r < 8; r++) { p1[r] = acc[r] * wa1; p2[r] = acc[r] * wa2; }
    #pragma unroll
    for (int off = 32; off > 0; off >>= 1) {
        #pragma unroll
        for (int r = 0; r < 8; r++) {
            p1[r] += __shfl_down(p1[r], off);
            p2[r] += __shfl_down(p2[r], off);
        }
    }
    const int wv = t >> 6, ln = t & 63;
    if (ln == 0) {
        #pragma unroll
        for (int r = 0; r < 8; r++) { red[0][r][wv] = p1[r]; red[1][r][wv] = p2[r]; }
    }
    __syncthreads();
    if (t < 16) {
        const int s = t >> 3, r = t & 7;
        float v = red[s][r][0] + red[s][r][1] + red[s][r][2] + red[s][r][3];
        v += s ? ba2[0] : ba1[0];
        if (s) s2[r0 + r] = v; else s1[r0 + r] = v;
    }
}

// ---------------- Kernel A2: smax = max(s2) ----------------
__global__ __launch_bounds__(256) void smax_kernel(const float* __restrict__ s2,
                                                   float* __restrict__ smax)
{
    __shared__ float red[4];
    float m = -1e30f;
    for (int i = threadIdx.x; i < NN; i += 256) m = fmaxf(m, s2[i]);
    #pragma unroll
    for (int off = 32; off > 0; off >>= 1) m = fmaxf(m, __shfl_down(m, off));
    if ((threadIdx.x & 63) == 0) red[threadIdx.x >> 6] = m;
    __syncthreads();
    if (threadIdx.x == 0)
        smax[0] = fmaxf(fmaxf(red[0], red[1]), fmaxf(red[2], red[3]));
}

// ---------------- Kernel B: fused {adj ballot-pack} + {masked softmax-num @ h} ----------------
// grid (128, 4), 512 threads = 8 waves: 4 row-groups x 2 col-halves.
// Wave w: rows (w>>1)*16..+16, cols (w&1)*128..+128 of the 64x256 block tile.
// Phase 1: ballot-pack block's 512KB adj slice -> 16.9KB LDS bitmask (1 barrier).
// Phase 2: barrier-free; acc[8] per wave; B-frags direct from L1/L2-resident hb.
__global__ __launch_bounds__(512, 4) void attn_kernel(
    const int* __restrict__ adj, const uint4* __restrict__ hb,
    const float* __restrict__ s1, const float* __restrict__ s2,
    const float* __restrict__ smaxp, float* __restrict__ outp,
    float* __restrict__ pbase, float* __restrict__ rs)
{
    __shared__ float s2l[JRANGE];                     // 8 KB (pre-scaled by log2e)
    __shared__ unsigned long long mask_lds[64][33];   // 16.9 KB (pad: bank spread)

    const int t = threadIdx.x;
    const int wave = t >> 6, lane = t & 63;
    const int wr = wave >> 1;          // row-group 0..3
    const int ch = wave & 1;           // col-half 0..1
    const int g = lane >> 4, lr = lane & 15;
    const int jq = blockIdx.y;
    const int Jbase = jq * JRANGE;
    const int R0 = blockIdx.x * 64;
    const int row = R0 + wr * 16 + lr;

    // stage s2 slice, pre-scaled by log2(e): one float4 per thread
    {
        const float4 v = ((const float4*)(s2 + Jbase))[t];
        ((float4*)s2l)[t] = make_float4(v.x * L2E, v.y * L2E, v.z * L2E, v.w * L2E);
    }

    // ---- Phase 1: ballot-pack. 8 waves x 8 rows; per row 32 coalesced dword bursts ----
    {
        const int prow0 = wave * 8;
        for (int r = 0; r < 8; ++r) {
            const int* arow = adj + (size_t)(R0 + prow0 + r) * NN + Jbase + lane;
            int v[32];
            #pragma unroll
            for (int c = 0; c < 32; ++c)
                v[c] = __builtin_nontemporal_load(arow + c * 64);
            unsigned long long myw = 0;
            #pragma unroll
            for (int c = 0; c < 32; ++c) {
                const unsigned long long m = __ballot(v[c] > 0);
                if (lane == c) myw = m;
            }
            if (lane < 32) mask_lds[prow0 + r][lane] = myw;
        }
    }

    const float my_s1 = s1[row] * L2E;
    const float z0 = my_s1 + smaxp[0] * L2E;
    const float m_i = fmaxf(z0, 0.01f * z0);   // scaled upper bound of masked row max

    f32x4 acc[8];
    #pragma unroll
    for (int n = 0; n < 8; n++) acc[n] = (f32x4)(0.f);
    float rsum = 0.f;

    const uint4* hb_base = hb + (size_t)(Jbase >> 5) * 1024 + ch * 128;

    __syncthreads();   // mask + s2l ready (only barrier in the kernel)

    // ---- Phase 2: barrier-free MFMA tile loop, B-frags straight from L1/L2 ----
    for (int tt = 0; tt < NT; ++tt) {
        const unsigned long long m64 = mask_lds[wr * 16 + lr][tt >> 1];
        const unsigned mb = (unsigned)(m64 >> ((tt & 1) * 32 + g * 8)) & 0xFFu;

        const int j0 = tt * 32 + g * 8;
        const float4 sva = *(const float4*)(s2l + j0);
        const float4 svb = *(const float4*)(s2l + j0 + 4);
        const float sv[8] = {sva.x, sva.y, sva.z, sva.w, svb.x, svb.y, svb.z, svb.w};
        union { ushort u[8]; s16x8 v; } pk;
        #pragma unroll
        for (int e = 0; e < 8; e++) {
            const float zz = my_s1 + sv[e];
            const float ee = fmaxf(zz, 0.01f * zz);   // leaky_relu (log2-scaled)
            float p = exp2f(ee - m_i);
            p = ((mb >> e) & 1u) ? p : 0.f;
            rsum += p;
            pk.u[e] = f2bf(p);
        }
        const s16x8 afrag = pk.v;

        const uint4* bsrc = hb_base + (size_t)tt * 1024 + g * 256 + lr;
        uint4 bf[4];
        #pragma unroll
        for (int n = 0; n < 4; n++) bf[n] = bsrc[n * 16];
        #pragma unroll
        for (int n = 0; n < 4; n++)
            acc[n] = __builtin_amdgcn_mfma_f32_16x16x32_bf16(afrag, *(const s16x8*)&bf[n], acc[n], 0, 0, 0);
        #pragma unroll
        for (int n = 0; n < 4; n++) bf[n] = bsrc[64 + n * 16];
        #pragma unroll
        for (int n = 0; n < 4; n++)
            acc[n + 4] = __builtin_amdgcn_mfma_f32_16x16x32_bf16(afrag, *(const s16x8*)&bf[n], acc[n + 4], 0, 0, 0);
    }

    // row-sum reduce across the 4 k-groups (once per row; col-half 0 only)
    rsum += __shfl_xor(rsum, 16);
    rsum += __shfl_xor(rsum, 32);
    if (ch == 0 && g == 0) rs[(size_t)jq * NN + row] = rsum;

    float* dst = (jq == 0) ? outp : (pbase + (size_t)(jq - 1) * ((size_t)NN * OUT_C));
    #pragma unroll
    for (int r = 0; r < 4; r++) {
        const int orow = R0 + wr * 16 + g * 4 + r;
        float* op = dst + (size_t)orow * OUT_C + ch * 128 + lr;
        #pragma unroll
        for (int n = 0; n < 8; n++)
            __builtin_nontemporal_store(acc[n][r], op + n * 16);
    }
}

// ---------------- Kernel C: combine partials, normalize ----------------
__global__ __launch_bounds__(256) void combine_kernel(
    float* __restrict__ out, const float* __restrict__ pbase,
    const float* __restrict__ rs)
{
    const int row = blockIdx.x, t = threadIdx.x;
    float rsum = 0.f;
    #pragma unroll
    for (int q = 0; q < JSPL; q++) rsum += rs[(size_t)q * NN + row];
    const float inv = 1.f / rsum;
    const size_t idx = (size_t)row * OUT_C + t;
    const size_t stride = (size_t)NN * OUT_C;
    float v = out[idx];
    #pragma unroll
    for (int q = 0; q < JSPL - 1; q++)
        v += __builtin_nontemporal_load(&pbase[idx + (size_t)q * stride]);
    out[idx] = v * inv;
}

extern "C" void kernel_launch(void* const* d_in, const int* in_sizes, int n_in,
                              void* d_out, int out_size, void* d_ws, size_t ws_size,
                              hipStream_t stream) {
    const float* x   = (const float*)d_in[0];
    const int*   adj = (const int*)d_in[1];
    const float* Wfc = (const float*)d_in[2];
    const float* bfc = (const float*)d_in[3];
    const float* Wa1 = (const float*)d_in[4];
    const float* ba1 = (const float*)d_in[5];
    const float* Wa2 = (const float*)d_in[6];
    const float* ba2 = (const float*)d_in[7];
    float* out = (float*)d_out;

    char* ws = (char*)d_ws;
    uint4* hb   = (uint4*)ws;                        // 4 MiB   [256][4][256] uint4
    float* s1   = (float*)(ws + (4u << 20));         // 32 KiB
    float* s2   = s1 + NN;                           // 32 KiB
    float* rs   = s2 + NN;                           // 128 KiB [4][8192]
    float* smax = rs + JSPL * NN;                    // 4 B
    float* pbase = (float*)(ws + (5u << 20));        // 24 MiB  [3][8192][256] f32

    fc_kernel<<<dim3(NN / 8), 256, 0, stream>>>(x, Wfc, bfc, Wa1, ba1, Wa2, ba2, hb, s1, s2);
    smax_kernel<<<dim3(1), 256, 0, stream>>>(s2, smax);
    attn_kernel<<<dim3(NN / 64, JSPL), 512, 0, stream>>>(adj, hb, s1, s2, smax, out, pbase, rs);
    combine_kernel<<<dim3(NN), 256, 0, stream>>>(out, pbase, rs);
}